// Round 1
// baseline (28868.762 us; speedup 1.0000x reference)
//
#include <hip/hip_runtime.h>
#include <hip/hip_cooperative_groups.h>

namespace cg = cooperative_groups;

#define NT 499    // T-1 sequential steps
#define NB 64     // batch (= wave size, lane = b)
#define NN 512    // region width
#define ND 100    // input dim
#define NO 10     // output dim

// workspace layout (floats)
#define XT_SZ   (NT * ND * NB)     // 3,193,600  : XT[t][d][b] = X[t+1][b][d]
#define RBUF_SZ (2 * NN * NB)      // 65,536     : double-buffered rT[buf][n][b]
#define XT_OFF  0
#define RM_OFF  (XT_OFF + XT_SZ)
#define RP_OFF  (RM_OFF + RBUF_SZ)
#define RS_OFF  (RP_OFF + RBUF_SZ)

// Transpose X[t+1][b][d] -> XT[t][d][b] so the main loop's lane=b loads coalesce.
__global__ void xpose_kernel(const float* __restrict__ X, float* __restrict__ XT) {
  __shared__ float tile[NB * ND];
  const int t = blockIdx.x;                       // 0..NT-1
  const float* src = X + (size_t)(t + 1) * NB * ND;
  for (int i = threadIdx.x; i < NB * ND; i += blockDim.x) tile[i] = src[i];
  __syncthreads();
  float* dst = XT + (size_t)t * ND * NB;
  for (int i = threadIdx.x; i < NB * ND; i += blockDim.x) {
    const int d = i >> 6, b = i & 63;
    dst[i] = tile[b * ND + d];
  }
}

// Persistent cooperative kernel: 256 WGs x 256 threads (1 WG/CU, 1 wave/SIMD).
// WG g owns columns n0=2g, n0+1 of all three regions (12 source-units: balanced).
// Waves k-split (128 each), LDS reduce, wave0 keeps x-state in registers.
__global__ void __launch_bounds__(256, 1)
rnn_kernel(const float* __restrict__ XT,
           float* __restrict__ r_m1, float* __restrict__ r_pmd, float* __restrict__ r_s1,
           const float* __restrict__ W_rec_m1, const float* __restrict__ W_rec_pmd,
           const float* __restrict__ W_rec_s1,
           const float* __restrict__ b_m1, const float* __restrict__ b_pmd,
           const float* __restrict__ b_s1,
           const float* __restrict__ W_pmd_m1, const float* __restrict__ W_s1_m1,
           const float* __restrict__ W_m1_pmd, const float* __restrict__ W_in_pmd,
           const float* __restrict__ W_in_s1, const float* __restrict__ W_out,
           float* __restrict__ out)
{
  cg::grid_group grid = cg::this_grid();
  const int g    = blockIdx.x;
  const int wave = threadIdx.x >> 6;
  const int lane = threadIdx.x & 63;
  const int n0 = 2 * g, n1 = 2 * g + 1;
  const int k0 = wave * 128;
  const int d0 = wave * 25;
  const bool has_out = (g < NO);

  __shared__ float red[4][7][64];

  // r buffers are poisoned before every launch: zero slot 0 (initial state r=tanh(0)=0)
  for (int i = blockIdx.x * blockDim.x + threadIdx.x; i < NN * NB;
       i += gridDim.x * blockDim.x) {
    r_m1[i] = 0.f; r_pmd[i] = 0.f; r_s1[i] = 0.f;
  }

  // wave-uniform scalars / row pointers (compiler scalarizes -> s_load streams)
  const float bm0 = b_m1[n0],  bm1 = b_m1[n1];
  const float bp0 = b_pmd[n0], bp1 = b_pmd[n1];
  const float bs0 = b_s1[n0],  bs1 = b_s1[n1];
  const float* wrm0 = W_rec_m1 + (size_t)n0 * NN + k0;
  const float* wrm1 = W_rec_m1 + (size_t)n1 * NN + k0;
  const float* wmp0 = W_m1_pmd + (size_t)n0 * NN + k0;
  const float* wmp1 = W_m1_pmd + (size_t)n1 * NN + k0;
  const float* wpm0 = W_pmd_m1 + (size_t)n0 * NN + k0;
  const float* wpm1 = W_pmd_m1 + (size_t)n1 * NN + k0;
  const float* wrp0 = W_rec_pmd + (size_t)n0 * NN + k0;
  const float* wrp1 = W_rec_pmd + (size_t)n1 * NN + k0;
  const float* wsm0 = W_s1_m1 + (size_t)n0 * NN + k0;
  const float* wsm1 = W_s1_m1 + (size_t)n1 * NN + k0;
  const float* wrs0 = W_rec_s1 + (size_t)n0 * NN + k0;
  const float* wrs1 = W_rec_s1 + (size_t)n1 * NN + k0;
  const float* wip0 = W_in_pmd + (size_t)n0 * ND + d0;
  const float* wip1 = W_in_pmd + (size_t)n1 * ND + d0;
  const float* wis0 = W_in_s1 + (size_t)n0 * ND + d0;
  const float* wis1 = W_in_s1 + (size_t)n1 * ND + d0;
  const float* wo   = W_out + (size_t)(has_out ? g : 0) * NN + k0;

  // persistent x-state (wave 0 of each WG owns it; lane = b)
  float xm0 = 0.f, xm1 = 0.f, xp0 = 0.f, xp1 = 0.f, xs0 = 0.f, xs1 = 0.f;

  __threadfence();
  grid.sync();

  for (int ti = 0; ti < NT; ++ti) {
    const int cur = ti & 1, nxt = cur ^ 1;
    const float* rm = r_m1 + cur * NN * NB + k0 * NB + lane;
    const float* rp = r_pmd + cur * NN * NB + k0 * NB + lane;
    const float* rs = r_s1 + cur * NN * NB + k0 * NB + lane;
    float am0 = 0.f, am1 = 0.f, ap0 = 0.f, ap1 = 0.f, as0 = 0.f, as1 = 0.f, ao = 0.f;

    // source r_m1 -> m1(rec), pmd(m1->pmd)
    #pragma unroll 8
    for (int k = 0; k < 128; ++k) {
      const float v = rm[k * NB];
      am0 = fmaf(v, wrm0[k], am0);
      am1 = fmaf(v, wrm1[k], am1);
      ap0 = fmaf(v, wmp0[k], ap0);
      ap1 = fmaf(v, wmp1[k], ap1);
    }
    // output GEMM rides on WGs 0..9 (rm slice is L1-hot)
    if (has_out) {
      #pragma unroll 8
      for (int k = 0; k < 128; ++k) ao = fmaf(rm[k * NB], wo[k], ao);
    }
    // source r_pmd -> m1(pmd->m1), pmd(rec)
    #pragma unroll 8
    for (int k = 0; k < 128; ++k) {
      const float v = rp[k * NB];
      am0 = fmaf(v, wpm0[k], am0);
      am1 = fmaf(v, wpm1[k], am1);
      ap0 = fmaf(v, wrp0[k], ap0);
      ap1 = fmaf(v, wrp1[k], ap1);
    }
    // source r_s1 -> m1(s1->m1), s1(rec)
    #pragma unroll 8
    for (int k = 0; k < 128; ++k) {
      const float v = rs[k * NB];
      am0 = fmaf(v, wsm0[k], am0);
      am1 = fmaf(v, wsm1[k], am1);
      as0 = fmaf(v, wrs0[k], as0);
      as1 = fmaf(v, wrs1[k], as1);
    }
    // source Xt -> pmd, s1 (K=100 split 25/wave)
    {
      const float* xt = XT + (size_t)ti * ND * NB + d0 * NB + lane;
      #pragma unroll
      for (int d = 0; d < 25; ++d) {
        const float v = xt[d * NB];
        ap0 = fmaf(v, wip0[d], ap0);
        ap1 = fmaf(v, wip1[d], ap1);
        as0 = fmaf(v, wis0[d], as0);
        as1 = fmaf(v, wis1[d], as1);
      }
    }

    red[wave][0][lane] = am0; red[wave][1][lane] = am1;
    red[wave][2][lane] = ap0; red[wave][3][lane] = ap1;
    red[wave][4][lane] = as0; red[wave][5][lane] = as1;
    red[wave][6][lane] = ao;
    __syncthreads();

    if (wave == 0) {
      const float sm0 = red[0][0][lane] + red[1][0][lane] + red[2][0][lane] + red[3][0][lane];
      const float sm1 = red[0][1][lane] + red[1][1][lane] + red[2][1][lane] + red[3][1][lane];
      const float sp0 = red[0][2][lane] + red[1][2][lane] + red[2][2][lane] + red[3][2][lane];
      const float sp1 = red[0][3][lane] + red[1][3][lane] + red[2][3][lane] + red[3][3][lane];
      const float ss0 = red[0][4][lane] + red[1][4][lane] + red[2][4][lane] + red[3][4][lane];
      const float ss1 = red[0][5][lane] + red[1][5][lane] + red[2][5][lane] + red[3][5][lane];
      xm0 = 0.9f * xm0 + 0.1f * (sm0 + bm0);
      xm1 = 0.9f * xm1 + 0.1f * (sm1 + bm1);
      xp0 = 0.9f * xp0 + 0.1f * (sp0 + bp0);
      xp1 = 0.9f * xp1 + 0.1f * (sp1 + bp1);
      xs0 = 0.9f * xs0 + 0.1f * (ss0 + bs0);
      xs1 = 0.9f * xs1 + 0.1f * (ss1 + bs1);
      float* rmw = r_m1 + nxt * NN * NB;
      float* rpw = r_pmd + nxt * NN * NB;
      float* rsw = r_s1 + nxt * NN * NB;
      rmw[n0 * NB + lane] = tanhf(xm0);
      rmw[n1 * NB + lane] = tanhf(xm1);
      rpw[n0 * NB + lane] = tanhf(xp0);
      rpw[n1 * NB + lane] = tanhf(xp1);
      rsw[n0 * NB + lane] = tanhf(xs0);
      rsw[n1 * NB + lane] = tanhf(xs1);
      if (has_out && ti > 0) {
        const float so = red[0][6][lane] + red[1][6][lane] + red[2][6][lane] + red[3][6][lane];
        out[(size_t)(ti - 1) * (NB * NO) + lane * NO + g] = so;   // out[ti-1][b][o]
      }
      __threadfence();
    }
    grid.sync();
  }

  // epilogue: out[NT-1] from final r_m1 (lives in buffer NT&1 after the loop)
  if (has_out) {
    const float* rm = r_m1 + (NT & 1) * NN * NB + k0 * NB + lane;
    float ao = 0.f;
    #pragma unroll 8
    for (int k = 0; k < 128; ++k) ao = fmaf(rm[k * NB], wo[k], ao);
    red[wave][6][lane] = ao;
    __syncthreads();
    if (wave == 0) {
      const float so = red[0][6][lane] + red[1][6][lane] + red[2][6][lane] + red[3][6][lane];
      out[(size_t)(NT - 1) * (NB * NO) + lane * NO + g] = so;
    }
  }
}

extern "C" void kernel_launch(void* const* d_in, const int* in_sizes, int n_in,
                              void* d_out, int out_size, void* d_ws, size_t ws_size,
                              hipStream_t stream) {
  (void)in_sizes; (void)n_in; (void)out_size; (void)ws_size;
  const float* X         = (const float*)d_in[0];
  const float* W_rec_m1  = (const float*)d_in[1];
  const float* W_rec_pmd = (const float*)d_in[2];
  const float* W_rec_s1  = (const float*)d_in[3];
  const float* b_m1      = (const float*)d_in[4];
  const float* b_pmd     = (const float*)d_in[5];
  const float* b_s1      = (const float*)d_in[6];
  const float* W_pmd_m1  = (const float*)d_in[7];
  const float* W_s1_m1   = (const float*)d_in[8];
  const float* W_m1_pmd  = (const float*)d_in[9];
  const float* W_in_pmd  = (const float*)d_in[10];
  const float* W_in_s1   = (const float*)d_in[11];
  const float* W_out     = (const float*)d_in[12];
  float* out = (float*)d_out;

  float* wsf = (float*)d_ws;
  const float* XT = wsf + XT_OFF;
  float* XTw  = wsf + XT_OFF;
  float* r_m1 = wsf + RM_OFF;
  float* r_pmd = wsf + RP_OFF;
  float* r_s1 = wsf + RS_OFF;

  xpose_kernel<<<NT, 256, 0, stream>>>(X, XTw);

  void* args[17];
  args[0]  = (void*)&XT;
  args[1]  = (void*)&r_m1;  args[2]  = (void*)&r_pmd; args[3]  = (void*)&r_s1;
  args[4]  = (void*)&W_rec_m1; args[5] = (void*)&W_rec_pmd; args[6] = (void*)&W_rec_s1;
  args[7]  = (void*)&b_m1;  args[8]  = (void*)&b_pmd; args[9]  = (void*)&b_s1;
  args[10] = (void*)&W_pmd_m1; args[11] = (void*)&W_s1_m1; args[12] = (void*)&W_m1_pmd;
  args[13] = (void*)&W_in_pmd; args[14] = (void*)&W_in_s1; args[15] = (void*)&W_out;
  args[16] = (void*)&out;
  hipLaunchCooperativeKernel((const void*)rnn_kernel, dim3(256), dim3(256), args, 0, stream);
}

// Round 2
// 14806.546 us; speedup vs baseline: 1.9497x; 1.9497x over previous
//
#include <hip/hip_runtime.h>
#include <hip/hip_cooperative_groups.h>

namespace cg = cooperative_groups;

#define NT 499    // T-1 sequential steps
#define NB 64     // batch (= wave size, lane = b)
#define NN 512    // region width
#define ND 100    // input dim
#define NO 10     // output dim

// workspace layout (floats)
#define XT_SZ   (NT * ND * NB)     // XT[t][d][b] = X[t+1][b][d]
#define RBUF_SZ (2 * NN * NB)      // double-buffered rT[buf][n][b]
#define XT_OFF  0
#define RM_OFF  (XT_OFF + XT_SZ)
#define RP_OFF  (RM_OFF + RBUF_SZ)
#define RS_OFF  (RP_OFF + RBUF_SZ)
#define FLAG_OFF (RS_OFF + RBUF_SZ)   // 256 arrival flags + 1 gen word

// Transpose X[t+1][b][d] -> XT[t][d][b] so the main loop's lane=b loads coalesce.
__global__ void xpose_kernel(const float* __restrict__ X, float* __restrict__ XT) {
  __shared__ float tile[NB * ND];
  const int t = blockIdx.x;
  const float* src = X + (size_t)(t + 1) * NB * ND;
  for (int i = threadIdx.x; i < NB * ND; i += blockDim.x) tile[i] = src[i];
  __syncthreads();
  float* dst = XT + (size_t)t * ND * NB;
  for (int i = threadIdx.x; i < NB * ND; i += blockDim.x) {
    const int d = i >> 6, b = i & 63;
    dst[i] = tile[b * ND + d];
  }
}

// Persistent cooperative kernel: 256 WGs x 512 threads (8 waves = 2 waves/SIMD).
// WG g owns columns n0=2g, n0+1 of all three regions. Waves k-split 8x64,
// LDS reduce, wave0 keeps x-state in registers. Custom flag-based grid barrier
// (cg::grid.sync measured ~54us/step in R1 -> replace).
__global__ void __launch_bounds__(512)
rnn_kernel(const float* __restrict__ XT,
           float* __restrict__ r_m1, float* __restrict__ r_pmd, float* __restrict__ r_s1,
           const float* __restrict__ W_rec_m1, const float* __restrict__ W_rec_pmd,
           const float* __restrict__ W_rec_s1,
           const float* __restrict__ b_m1, const float* __restrict__ b_pmd,
           const float* __restrict__ b_s1,
           const float* __restrict__ W_pmd_m1, const float* __restrict__ W_s1_m1,
           const float* __restrict__ W_m1_pmd, const float* __restrict__ W_in_pmd,
           const float* __restrict__ W_in_s1, const float* __restrict__ W_out,
           float* __restrict__ out,
           unsigned* __restrict__ flags, unsigned* __restrict__ gen)
{
  const int g    = blockIdx.x;
  const int wave = threadIdx.x >> 6;
  const int lane = threadIdx.x & 63;
  const int n0 = 2 * g, n1 = 2 * g + 1;
  const int k0 = wave * 64;
  const int d0 = wave * 13;
  const int dlen = (ND - d0 < 13) ? (ND - d0) : 13;   // waves0-6:13, wave7:9
  const bool has_out = (g < NO);

  __shared__ float red[8][7][64];

  // ws is poisoned before every launch: zero r slot 0 and barrier words.
  for (int i = g * (int)blockDim.x + (int)threadIdx.x; i < NN * NB;
       i += (int)(gridDim.x * blockDim.x)) {
    r_m1[i] = 0.f; r_pmd[i] = 0.f; r_s1[i] = 0.f;
  }
  if (threadIdx.x == 0) flags[g] = 0u;
  if (g == 0 && threadIdx.x == 1) *gen = 0u;

  // wave-uniform weight row pointers (scalarized by compiler)
  const float bm0 = b_m1[n0],  bm1 = b_m1[n1];
  const float bp0 = b_pmd[n0], bp1 = b_pmd[n1];
  const float bs0 = b_s1[n0],  bs1 = b_s1[n1];
  const float* wrm0 = W_rec_m1 + (size_t)n0 * NN + k0;
  const float* wrm1 = W_rec_m1 + (size_t)n1 * NN + k0;
  const float* wmp0 = W_m1_pmd + (size_t)n0 * NN + k0;
  const float* wmp1 = W_m1_pmd + (size_t)n1 * NN + k0;
  const float* wpm0 = W_pmd_m1 + (size_t)n0 * NN + k0;
  const float* wpm1 = W_pmd_m1 + (size_t)n1 * NN + k0;
  const float* wrp0 = W_rec_pmd + (size_t)n0 * NN + k0;
  const float* wrp1 = W_rec_pmd + (size_t)n1 * NN + k0;
  const float* wsm0 = W_s1_m1 + (size_t)n0 * NN + k0;
  const float* wsm1 = W_s1_m1 + (size_t)n1 * NN + k0;
  const float* wrs0 = W_rec_s1 + (size_t)n0 * NN + k0;
  const float* wrs1 = W_rec_s1 + (size_t)n1 * NN + k0;
  const float* wip0 = W_in_pmd + (size_t)n0 * ND + d0;
  const float* wip1 = W_in_pmd + (size_t)n1 * ND + d0;
  const float* wis0 = W_in_s1 + (size_t)n0 * ND + d0;
  const float* wis1 = W_in_s1 + (size_t)n1 * ND + d0;
  const float* wo   = W_out + (size_t)(has_out ? g : 0) * NN + k0;

  // persistent x-state (wave0, lane = b)
  float xm0 = 0.f, xm1 = 0.f, xp0 = 0.f, xp1 = 0.f, xs0 = 0.f, xs1 = 0.f;

  // one-time heavyweight sync to order init (flags/r zeroing) grid-wide
  cg::this_grid().sync();

  for (int ti = 0; ti < NT; ++ti) {
    const int cur = ti & 1, nxt = cur ^ 1;
    const float* rm = r_m1 + cur * NN * NB + k0 * NB + lane;
    const float* rp = r_pmd + cur * NN * NB + k0 * NB + lane;
    const float* rs = r_s1 + cur * NN * NB + k0 * NB + lane;
    float am0 = 0.f, am1 = 0.f, ap0 = 0.f, ap1 = 0.f, as0 = 0.f, as1 = 0.f, ao = 0.f;

    // source r_m1 -> m1(rec), pmd(m1->pmd)
    #pragma unroll 16
    for (int k = 0; k < 64; ++k) {
      const float v = rm[k * NB];
      am0 = fmaf(v, wrm0[k], am0);
      am1 = fmaf(v, wrm1[k], am1);
      ap0 = fmaf(v, wmp0[k], ap0);
      ap1 = fmaf(v, wmp1[k], ap1);
    }
    if (has_out) {
      #pragma unroll 16
      for (int k = 0; k < 64; ++k) ao = fmaf(rm[k * NB], wo[k], ao);
    }
    // source r_pmd -> m1(pmd->m1), pmd(rec)
    #pragma unroll 16
    for (int k = 0; k < 64; ++k) {
      const float v = rp[k * NB];
      am0 = fmaf(v, wpm0[k], am0);
      am1 = fmaf(v, wpm1[k], am1);
      ap0 = fmaf(v, wrp0[k], ap0);
      ap1 = fmaf(v, wrp1[k], ap1);
    }
    // source r_s1 -> m1(s1->m1), s1(rec)
    #pragma unroll 16
    for (int k = 0; k < 64; ++k) {
      const float v = rs[k * NB];
      am0 = fmaf(v, wsm0[k], am0);
      am1 = fmaf(v, wsm1[k], am1);
      as0 = fmaf(v, wrs0[k], as0);
      as1 = fmaf(v, wrs1[k], as1);
    }
    // source Xt -> pmd, s1
    {
      const float* xt = XT + (size_t)ti * ND * NB + d0 * NB + lane;
      for (int d = 0; d < dlen; ++d) {
        const float v = xt[d * NB];
        ap0 = fmaf(v, wip0[d], ap0);
        ap1 = fmaf(v, wip1[d], ap1);
        as0 = fmaf(v, wis0[d], as0);
        as1 = fmaf(v, wis1[d], as1);
      }
    }

    red[wave][0][lane] = am0; red[wave][1][lane] = am1;
    red[wave][2][lane] = ap0; red[wave][3][lane] = ap1;
    red[wave][4][lane] = as0; red[wave][5][lane] = as1;
    red[wave][6][lane] = ao;
    __syncthreads();

    if (wave == 0) {
      float s[7];
      #pragma unroll
      for (int j = 0; j < 7; ++j) {
        float t = red[0][j][lane];
        #pragma unroll
        for (int w = 1; w < 8; ++w) t += red[w][j][lane];
        s[j] = t;
      }
      xm0 = 0.9f * xm0 + 0.1f * (s[0] + bm0);
      xm1 = 0.9f * xm1 + 0.1f * (s[1] + bm1);
      xp0 = 0.9f * xp0 + 0.1f * (s[2] + bp0);
      xp1 = 0.9f * xp1 + 0.1f * (s[3] + bp1);
      xs0 = 0.9f * xs0 + 0.1f * (s[4] + bs0);
      xs1 = 0.9f * xs1 + 0.1f * (s[5] + bs1);
      float* rmw = r_m1 + nxt * NN * NB;
      float* rpw = r_pmd + nxt * NN * NB;
      float* rsw = r_s1 + nxt * NN * NB;
      rmw[n0 * NB + lane] = tanhf(xm0);
      rmw[n1 * NB + lane] = tanhf(xm1);
      rpw[n0 * NB + lane] = tanhf(xp0);
      rpw[n1 * NB + lane] = tanhf(xp1);
      rsw[n0 * NB + lane] = tanhf(xs0);
      rsw[n1 * NB + lane] = tanhf(xs1);
      if (has_out && ti > 0) {
        out[(size_t)(ti - 1) * (NB * NO) + lane * NO + g] = s[6];
      }
    }

    // ---- custom grid barrier (publish + single-poller) ----
    __syncthreads();                       // WG done; wave0's r stores issued
    const unsigned tgt = (unsigned)ti + 1u;
    if (threadIdx.x == 0) {
      __threadfence();                     // release r writes device-wide
      __hip_atomic_store(&flags[g], tgt, __ATOMIC_RELAXED, __HIP_MEMORY_SCOPE_AGENT);
    }
    if (g == 0) {
      if (threadIdx.x < 256) {
        while (__hip_atomic_load(&flags[threadIdx.x], __ATOMIC_RELAXED,
                                 __HIP_MEMORY_SCOPE_AGENT) < tgt)
          __builtin_amdgcn_s_sleep(1);
      }
      __syncthreads();                     // all 256 arrivals observed
      if (threadIdx.x == 0) {
        __threadfence();                   // acquire r data / release gen
        __hip_atomic_store(gen, tgt, __ATOMIC_RELAXED, __HIP_MEMORY_SCOPE_AGENT);
      }
      __syncthreads();
    } else {
      if (threadIdx.x == 0) {
        while (__hip_atomic_load(gen, __ATOMIC_RELAXED,
                                 __HIP_MEMORY_SCOPE_AGENT) < tgt)
          __builtin_amdgcn_s_sleep(1);
        __threadfence();                   // acquire: invalidate stale r lines
      }
      __syncthreads();
    }
  }

  // epilogue: out[NT-1] from final r_m1
  if (has_out) {
    const float* rm = r_m1 + (NT & 1) * NN * NB + k0 * NB + lane;
    float ao = 0.f;
    #pragma unroll 16
    for (int k = 0; k < 64; ++k) ao = fmaf(rm[k * NB], wo[k], ao);
    red[wave][6][lane] = ao;
    __syncthreads();
    if (wave == 0) {
      float t = red[0][6][lane];
      #pragma unroll
      for (int w = 1; w < 8; ++w) t += red[w][6][lane];
      out[(size_t)(NT - 1) * (NB * NO) + lane * NO + g] = t;
    }
  }
}

extern "C" void kernel_launch(void* const* d_in, const int* in_sizes, int n_in,
                              void* d_out, int out_size, void* d_ws, size_t ws_size,
                              hipStream_t stream) {
  (void)in_sizes; (void)n_in; (void)out_size; (void)ws_size;
  const float* X         = (const float*)d_in[0];
  const float* W_rec_m1  = (const float*)d_in[1];
  const float* W_rec_pmd = (const float*)d_in[2];
  const float* W_rec_s1  = (const float*)d_in[3];
  const float* b_m1      = (const float*)d_in[4];
  const float* b_pmd     = (const float*)d_in[5];
  const float* b_s1      = (const float*)d_in[6];
  const float* W_pmd_m1  = (const float*)d_in[7];
  const float* W_s1_m1   = (const float*)d_in[8];
  const float* W_m1_pmd  = (const float*)d_in[9];
  const float* W_in_pmd  = (const float*)d_in[10];
  const float* W_in_s1   = (const float*)d_in[11];
  const float* W_out     = (const float*)d_in[12];
  float* out = (float*)d_out;

  float* wsf = (float*)d_ws;
  const float* XT = wsf + XT_OFF;
  float* XTw   = wsf + XT_OFF;
  float* r_m1  = wsf + RM_OFF;
  float* r_pmd = wsf + RP_OFF;
  float* r_s1  = wsf + RS_OFF;
  unsigned* flags = (unsigned*)(wsf + FLAG_OFF);
  unsigned* gen   = flags + 256;

  xpose_kernel<<<NT, 256, 0, stream>>>(X, XTw);

  void* args[19];
  args[0]  = (void*)&XT;
  args[1]  = (void*)&r_m1;  args[2]  = (void*)&r_pmd; args[3]  = (void*)&r_s1;
  args[4]  = (void*)&W_rec_m1; args[5] = (void*)&W_rec_pmd; args[6] = (void*)&W_rec_s1;
  args[7]  = (void*)&b_m1;  args[8]  = (void*)&b_pmd; args[9]  = (void*)&b_s1;
  args[10] = (void*)&W_pmd_m1; args[11] = (void*)&W_s1_m1; args[12] = (void*)&W_m1_pmd;
  args[13] = (void*)&W_in_pmd; args[14] = (void*)&W_in_s1; args[15] = (void*)&W_out;
  args[16] = (void*)&out;
  args[17] = (void*)&flags;
  args[18] = (void*)&gen;
  hipLaunchCooperativeKernel((const void*)rnn_kernel, dim3(256), dim3(512), args, 0, stream);
}

// Round 3
// 11258.443 us; speedup vs baseline: 2.5642x; 1.3152x over previous
//
#include <hip/hip_runtime.h>
#include <hip/hip_cooperative_groups.h>

namespace cg = cooperative_groups;

#define NT 499    // T-1 sequential steps
#define NB 64     // batch (= wave size, lane = b)
#define NN 512    // region width
#define ND 100    // input dim
#define NO 10     // output dim

// workspace layout (floats)
#define XT_SZ   (NT * ND * NB)     // XT[t][d][b] = X[t+1][b][d]
#define RBUF_SZ (2 * NN * NB)      // double-buffered rT[buf][n][b]
#define XT_OFF  0
#define RM_OFF  (XT_OFF + XT_SZ)
#define RP_OFF  (RM_OFF + RBUF_SZ)
#define RS_OFF  (RP_OFF + RBUF_SZ)
#define FLAG_OFF (RS_OFF + RBUF_SZ)   // 256 flags @ stride 16 words + 1 gen word

// Transpose X[t+1][b][d] -> XT[t][d][b] so the main loop's lane=b loads coalesce.
__global__ void xpose_kernel(const float* __restrict__ X, float* __restrict__ XT) {
  __shared__ float tile[NB * ND];
  const int t = blockIdx.x;
  const float* src = X + (size_t)(t + 1) * NB * ND;
  for (int i = threadIdx.x; i < NB * ND; i += blockDim.x) tile[i] = src[i];
  __syncthreads();
  float* dst = XT + (size_t)t * ND * NB;
  for (int i = threadIdx.x; i < NB * ND; i += blockDim.x) {
    const int d = i >> 6, b = i & 63;
    dst[i] = tile[b * ND + d];
  }
}

// Persistent cooperative kernel: 256 WGs x 512 threads (8 waves = 2 waves/SIMD).
// WG g owns columns n0=2g, n0+1 of all three regions. Waves k-split 8x64.
// KEY R3 change: k0/d0 forced wave-uniform via readfirstlane so all weight
// reads scalarize to s_load (K$-resident across steps) and the inner loop is
// v_fmac_f32 vdst, s_weight, v_r  (1 op/MAC, no per-lane weight addressing).
__global__ void __launch_bounds__(512)
rnn_kernel(const float* __restrict__ XT,
           float* __restrict__ r_m1, float* __restrict__ r_pmd, float* __restrict__ r_s1,
           const float* __restrict__ W_rec_m1, const float* __restrict__ W_rec_pmd,
           const float* __restrict__ W_rec_s1,
           const float* __restrict__ b_m1, const float* __restrict__ b_pmd,
           const float* __restrict__ b_s1,
           const float* __restrict__ W_pmd_m1, const float* __restrict__ W_s1_m1,
           const float* __restrict__ W_m1_pmd, const float* __restrict__ W_in_pmd,
           const float* __restrict__ W_in_s1, const float* __restrict__ W_out,
           float* __restrict__ out,
           unsigned* __restrict__ flags, unsigned* __restrict__ gen)
{
  const int g    = blockIdx.x;
  const int wave = __builtin_amdgcn_readfirstlane((int)threadIdx.x >> 6);
  const int lane = (int)threadIdx.x & 63;
  const int n0 = 2 * g, n1 = 2 * g + 1;
  const int k0 = __builtin_amdgcn_readfirstlane(wave * 64);
  const int d0 = __builtin_amdgcn_readfirstlane(wave * 13);
  const int dlen = (ND - d0 < 13) ? (ND - d0) : 13;   // waves0-6:13, wave7:9
  const bool has_out = (g < NO);

  __shared__ float red[8][7][64];

  // ws is poisoned before every launch: zero r slot 0 and barrier words.
  for (int i = g * (int)blockDim.x + (int)threadIdx.x; i < NN * NB;
       i += (int)(gridDim.x * blockDim.x)) {
    r_m1[i] = 0.f; r_pmd[i] = 0.f; r_s1[i] = 0.f;
  }
  if (threadIdx.x == 0) flags[g * 16] = 0u;
  if (g == 0 && threadIdx.x == 1) *gen = 0u;

  // wave-uniform weight row pointers -> scalar loads
  const float bm0 = b_m1[n0],  bm1 = b_m1[n1];
  const float bp0 = b_pmd[n0], bp1 = b_pmd[n1];
  const float bs0 = b_s1[n0],  bs1 = b_s1[n1];
  const float* wrm0 = W_rec_m1 + (size_t)n0 * NN + k0;
  const float* wrm1 = W_rec_m1 + (size_t)n1 * NN + k0;
  const float* wmp0 = W_m1_pmd + (size_t)n0 * NN + k0;
  const float* wmp1 = W_m1_pmd + (size_t)n1 * NN + k0;
  const float* wpm0 = W_pmd_m1 + (size_t)n0 * NN + k0;
  const float* wpm1 = W_pmd_m1 + (size_t)n1 * NN + k0;
  const float* wrp0 = W_rec_pmd + (size_t)n0 * NN + k0;
  const float* wrp1 = W_rec_pmd + (size_t)n1 * NN + k0;
  const float* wsm0 = W_s1_m1 + (size_t)n0 * NN + k0;
  const float* wsm1 = W_s1_m1 + (size_t)n1 * NN + k0;
  const float* wrs0 = W_rec_s1 + (size_t)n0 * NN + k0;
  const float* wrs1 = W_rec_s1 + (size_t)n1 * NN + k0;
  const float* wip0 = W_in_pmd + (size_t)n0 * ND + d0;
  const float* wip1 = W_in_pmd + (size_t)n1 * ND + d0;
  const float* wis0 = W_in_s1 + (size_t)n0 * ND + d0;
  const float* wis1 = W_in_s1 + (size_t)n1 * ND + d0;
  const float* wo   = W_out + (size_t)(has_out ? g : 0) * NN + k0;

  // persistent x-state (wave0, lane = b)
  float xm0 = 0.f, xm1 = 0.f, xp0 = 0.f, xp1 = 0.f, xs0 = 0.f, xs1 = 0.f;

  // one-time heavyweight sync to order init (flags/r zeroing) grid-wide
  cg::this_grid().sync();

  for (int ti = 0; ti < NT; ++ti) {
    const int cur = ti & 1, nxt = cur ^ 1;
    const float* rm = r_m1 + cur * NN * NB + k0 * NB + lane;
    const float* rp = r_pmd + cur * NN * NB + k0 * NB + lane;
    const float* rs = r_s1 + cur * NN * NB + k0 * NB + lane;
    float am0 = 0.f, am1 = 0.f, ap0 = 0.f, ap1 = 0.f, as0 = 0.f, as1 = 0.f, ao = 0.f;

    // source Xt -> pmd, s1 (HBM/L2-latency stream: issue first)
    {
      const float* xt = XT + (size_t)ti * ND * NB + d0 * NB + lane;
      for (int d = 0; d < dlen; ++d) {
        const float v = xt[d * NB];
        ap0 = fmaf(v, wip0[d], ap0);
        ap1 = fmaf(v, wip1[d], ap1);
        as0 = fmaf(v, wis0[d], as0);
        as1 = fmaf(v, wis1[d], as1);
      }
    }
    // source r_m1 -> m1(rec), pmd(m1->pmd)
    #pragma unroll 16
    for (int k = 0; k < 64; ++k) {
      const float v = rm[k * NB];
      am0 = fmaf(v, wrm0[k], am0);
      am1 = fmaf(v, wrm1[k], am1);
      ap0 = fmaf(v, wmp0[k], ap0);
      ap1 = fmaf(v, wmp1[k], ap1);
    }
    if (has_out) {
      #pragma unroll 16
      for (int k = 0; k < 64; ++k) ao = fmaf(rm[k * NB], wo[k], ao);
    }
    // source r_pmd -> m1(pmd->m1), pmd(rec)
    #pragma unroll 16
    for (int k = 0; k < 64; ++k) {
      const float v = rp[k * NB];
      am0 = fmaf(v, wpm0[k], am0);
      am1 = fmaf(v, wpm1[k], am1);
      ap0 = fmaf(v, wrp0[k], ap0);
      ap1 = fmaf(v, wrp1[k], ap1);
    }
    // source r_s1 -> m1(s1->m1), s1(rec)
    #pragma unroll 16
    for (int k = 0; k < 64; ++k) {
      const float v = rs[k * NB];
      am0 = fmaf(v, wsm0[k], am0);
      am1 = fmaf(v, wsm1[k], am1);
      as0 = fmaf(v, wrs0[k], as0);
      as1 = fmaf(v, wrs1[k], as1);
    }

    red[wave][0][lane] = am0; red[wave][1][lane] = am1;
    red[wave][2][lane] = ap0; red[wave][3][lane] = ap1;
    red[wave][4][lane] = as0; red[wave][5][lane] = as1;
    red[wave][6][lane] = ao;
    __syncthreads();

    if (wave == 0) {
      float s[7];
      #pragma unroll
      for (int j = 0; j < 7; ++j) {
        float t = red[0][j][lane];
        #pragma unroll
        for (int w = 1; w < 8; ++w) t += red[w][j][lane];
        s[j] = t;
      }
      xm0 = 0.9f * xm0 + 0.1f * (s[0] + bm0);
      xm1 = 0.9f * xm1 + 0.1f * (s[1] + bm1);
      xp0 = 0.9f * xp0 + 0.1f * (s[2] + bp0);
      xp1 = 0.9f * xp1 + 0.1f * (s[3] + bp1);
      xs0 = 0.9f * xs0 + 0.1f * (s[4] + bs0);
      xs1 = 0.9f * xs1 + 0.1f * (s[5] + bs1);
      float* rmw = r_m1 + nxt * NN * NB;
      float* rpw = r_pmd + nxt * NN * NB;
      float* rsw = r_s1 + nxt * NN * NB;
      rmw[n0 * NB + lane] = tanhf(xm0);
      rmw[n1 * NB + lane] = tanhf(xm1);
      rpw[n0 * NB + lane] = tanhf(xp0);
      rpw[n1 * NB + lane] = tanhf(xp1);
      rsw[n0 * NB + lane] = tanhf(xs0);
      rsw[n1 * NB + lane] = tanhf(xs1);
      if (has_out && ti > 0) {
        out[(size_t)(ti - 1) * (NB * NO) + lane * NO + g] = s[6];
      }
    }

    // ---- custom grid barrier (publish + single-poller), flags padded 64B ----
    __syncthreads();
    const unsigned tgt = (unsigned)ti + 1u;
    if (threadIdx.x == 0) {
      __threadfence();                     // release r writes device-wide
      __hip_atomic_store(&flags[g * 16], tgt, __ATOMIC_RELAXED, __HIP_MEMORY_SCOPE_AGENT);
    }
    if (g == 0) {
      if (threadIdx.x < 256) {
        while (__hip_atomic_load(&flags[threadIdx.x * 16], __ATOMIC_RELAXED,
                                 __HIP_MEMORY_SCOPE_AGENT) < tgt)
          __builtin_amdgcn_s_sleep(1);
      }
      __syncthreads();
      if (threadIdx.x == 0) {
        __threadfence();
        __hip_atomic_store(gen, tgt, __ATOMIC_RELAXED, __HIP_MEMORY_SCOPE_AGENT);
      }
      __syncthreads();
    } else {
      if (threadIdx.x == 0) {
        while (__hip_atomic_load(gen, __ATOMIC_RELAXED,
                                 __HIP_MEMORY_SCOPE_AGENT) < tgt)
          __builtin_amdgcn_s_sleep(1);
        __threadfence();                   // acquire: invalidate stale r lines
      }
      __syncthreads();
    }
  }

  // epilogue: out[NT-1] from final r_m1
  if (has_out) {
    const float* rm = r_m1 + (NT & 1) * NN * NB + k0 * NB + lane;
    float ao = 0.f;
    #pragma unroll 16
    for (int k = 0; k < 64; ++k) ao = fmaf(rm[k * NB], wo[k], ao);
    red[wave][6][lane] = ao;
    __syncthreads();
    if (wave == 0) {
      float t = red[0][6][lane];
      #pragma unroll
      for (int w = 1; w < 8; ++w) t += red[w][6][lane];
      out[(size_t)(NT - 1) * (NB * NO) + lane * NO + g] = t;
    }
  }
}

extern "C" void kernel_launch(void* const* d_in, const int* in_sizes, int n_in,
                              void* d_out, int out_size, void* d_ws, size_t ws_size,
                              hipStream_t stream) {
  (void)in_sizes; (void)n_in; (void)out_size; (void)ws_size;
  const float* X         = (const float*)d_in[0];
  const float* W_rec_m1  = (const float*)d_in[1];
  const float* W_rec_pmd = (const float*)d_in[2];
  const float* W_rec_s1  = (const float*)d_in[3];
  const float* b_m1      = (const float*)d_in[4];
  const float* b_pmd     = (const float*)d_in[5];
  const float* b_s1      = (const float*)d_in[6];
  const float* W_pmd_m1  = (const float*)d_in[7];
  const float* W_s1_m1   = (const float*)d_in[8];
  const float* W_m1_pmd  = (const float*)d_in[9];
  const float* W_in_pmd  = (const float*)d_in[10];
  const float* W_in_s1   = (const float*)d_in[11];
  const float* W_out     = (const float*)d_in[12];
  float* out = (float*)d_out;

  float* wsf = (float*)d_ws;
  const float* XT = wsf + XT_OFF;
  float* XTw   = wsf + XT_OFF;
  float* r_m1  = wsf + RM_OFF;
  float* r_pmd = wsf + RP_OFF;
  float* r_s1  = wsf + RS_OFF;
  unsigned* flags = (unsigned*)(wsf + FLAG_OFF);
  unsigned* gen   = flags + 256 * 16;

  xpose_kernel<<<NT, 256, 0, stream>>>(X, XTw);

  void* args[19];
  args[0]  = (void*)&XT;
  args[1]  = (void*)&r_m1;  args[2]  = (void*)&r_pmd; args[3]  = (void*)&r_s1;
  args[4]  = (void*)&W_rec_m1; args[5] = (void*)&W_rec_pmd; args[6] = (void*)&W_rec_s1;
  args[7]  = (void*)&b_m1;  args[8]  = (void*)&b_pmd; args[9]  = (void*)&b_s1;
  args[10] = (void*)&W_pmd_m1; args[11] = (void*)&W_s1_m1; args[12] = (void*)&W_m1_pmd;
  args[13] = (void*)&W_in_pmd; args[14] = (void*)&W_in_s1; args[15] = (void*)&W_out;
  args[16] = (void*)&out;
  args[17] = (void*)&flags;
  args[18] = (void*)&gen;
  hipLaunchCooperativeKernel((const void*)rnn_kernel, dim3(256), dim3(512), args, 0, stream);
}